// Round 11
// baseline (1684.680 us; speedup 1.0000x reference)
//
#include <hip/hip_runtime.h>

#define B_ 16
#define N_ 4096
#define S_ 1024
#define K_ 32
#define NSLOT 128
#define CNT_F 524288.0f   // B*S*K
#define RWS 524288        // total rows = B*S*K

typedef unsigned short ushort_t;

__device__ __forceinline__ ushort_t f2bf(float f) {
  unsigned u = __float_as_uint(f);
  unsigned r = (u + 0x7fffu + ((u >> 16) & 1u)) >> 16;
  return (ushort_t)r;
}

// ---------------------------------------------------------------- FPS
#define FPS_T 256
#define FPS_P (N_ / FPS_T)
#define FPS_W (FPS_T / 64)

template <int CTRL>
__device__ __forceinline__ void dpp_max_u64(unsigned& hi, unsigned& lo) {
  unsigned h2 = (unsigned)__builtin_amdgcn_update_dpp(0, (int)hi, CTRL, 0xf, 0xf, true);
  unsigned l2 = (unsigned)__builtin_amdgcn_update_dpp(0, (int)lo, CTRL, 0xf, 0xf, true);
  bool take = (h2 > hi) || (h2 == hi && l2 > lo);
  hi = take ? h2 : hi;
  lo = take ? l2 : lo;
}

__global__ __launch_bounds__(FPS_T) void fps_kernel(
    const float* __restrict__ xyz, int* __restrict__ fps_idx,
    float* __restrict__ out_newxyz) {
  __shared__ float xyz_s[N_ * 3];
  __shared__ int idx_s[S_];
  __shared__ unsigned long long keys_s[2][FPS_W];
  int b = blockIdx.x, t = threadIdx.x;
  const float* xb = xyz + (size_t)b * N_ * 3;
  for (int i = t; i < N_ * 3; i += FPS_T) xyz_s[i] = xb[i];
  __syncthreads();
  float px[FPS_P], py[FPS_P], pz[FPS_P], dd[FPS_P];
#pragma unroll
  for (int j = 0; j < FPS_P; ++j) {
    int n = t + j * FPS_T;
    px[j] = xyz_s[n * 3 + 0];
    py[j] = xyz_s[n * 3 + 1];
    pz[j] = xyz_s[n * 3 + 2];
    dd[j] = 1e10f;
  }
  int fi = 0;
#pragma unroll 1
  for (int s = 0; s < S_; ++s) {
    if (t == 0) idx_s[s] = fi;
    float cx = xyz_s[fi * 3 + 0], cy = xyz_s[fi * 3 + 1], cz = xyz_s[fi * 3 + 2];
    float bv = -1.0f;
    int bi = 0;
#pragma unroll
    for (int j = 0; j < FPS_P; ++j) {
      float dx = __fsub_rn(px[j], cx);
      float dy = __fsub_rn(py[j], cy);
      float dz = __fsub_rn(pz[j], cz);
      float d = __fadd_rn(__fadd_rn(__fmul_rn(dx, dx), __fmul_rn(dy, dy)),
                          __fmul_rn(dz, dz));
      d = fminf(dd[j], d);
      dd[j] = d;
      if (d > bv) { bv = d; bi = t + j * FPS_T; }
    }
    unsigned hi = __float_as_uint(bv);
    unsigned lo = (unsigned)(N_ - 1 - bi);
    dpp_max_u64<0x111>(hi, lo);
    dpp_max_u64<0x112>(hi, lo);
    dpp_max_u64<0x114>(hi, lo);
    dpp_max_u64<0x118>(hi, lo);
    dpp_max_u64<0x142>(hi, lo);
    dpp_max_u64<0x143>(hi, lo);
    unsigned whi = (unsigned)__builtin_amdgcn_readlane((int)hi, 63);
    unsigned wlo = (unsigned)__builtin_amdgcn_readlane((int)lo, 63);
    if ((t & 63) == 0)
      keys_s[s & 1][t >> 6] = ((unsigned long long)whi << 32) | wlo;
    __syncthreads();
    unsigned long long m = keys_s[s & 1][0];
#pragma unroll
    for (int w = 1; w < FPS_W; ++w) {
      unsigned long long k = keys_s[s & 1][w];
      m = k > m ? k : m;
    }
    fi = (N_ - 1) - (int)(unsigned)(m & 0xFFFFFFFFULL);
  }
  __syncthreads();
  for (int s = t; s < S_; s += FPS_T) {
    int i = idx_s[s];
    fps_idx[b * S_ + s] = i;
    out_newxyz[((size_t)b * S_ + s) * 3 + 0] = xyz_s[i * 3 + 0];
    out_newxyz[((size_t)b * S_ + s) * 3 + 1] = xyz_s[i * 3 + 1];
    out_newxyz[((size_t)b * S_ + s) * 3 + 2] = xyz_s[i * 3 + 2];
  }
}

// ---------------------------------------------------------------- point norms
__global__ void ptnorm_kernel(const float* __restrict__ xyz, float* __restrict__ pt) {
  int i = blockIdx.x * 256 + threadIdx.x;
  float x = xyz[(size_t)i * 3 + 0];
  float y = xyz[(size_t)i * 3 + 1];
  float z = xyz[(size_t)i * 3 + 2];
  pt[i] = __fadd_rn(__fadd_rn(__fmul_rn(x, x), __fmul_rn(y, y)), __fmul_rn(z, z));
}

// ---------------------------------------------------------------- kNN (K=32)
__global__ __launch_bounds__(64) void knn_kernel(
    const float* __restrict__ xyz, const float* __restrict__ ptnorm,
    const float* __restrict__ newxyz, const int* __restrict__ fps_idx,
    int* __restrict__ nn_idx) {
  int bs = blockIdx.x;
  int b = bs >> 10;
  int lane = threadIdx.x;
  float sx = newxyz[(size_t)bs * 3 + 0];
  float sy = newxyz[(size_t)bs * 3 + 1];
  float sz = newxyz[(size_t)bs * 3 + 2];
  int fi = fps_idx[bs];
  float nxn = ptnorm[(size_t)b * N_ + fi];
  const float* xb = xyz + (size_t)b * N_ * 3;
  const float* pnb = ptnorm + (size_t)b * N_;
  unsigned u[64];
#pragma unroll
  for (int j = 0; j < 64; ++j) {
    int n = j * 64 + lane;
    float x = xb[n * 3 + 0], y = xb[n * 3 + 1], z = xb[n * 3 + 2];
    float e = __fadd_rn(__fadd_rn(__fmul_rn(sx, x), __fmul_rn(sy, y)),
                        __fmul_rn(sz, z));
    float d = __fadd_rn(__fadd_rn(nxn, pnb[n]), __fmul_rn(-2.0f, e));
    int sb = __float_as_int(d);
    u[j] = (sb < 0) ? ~((unsigned)sb) : (((unsigned)sb) | 0x80000000u);
  }
  unsigned keep = 0;
#pragma unroll 1
  for (int p = 0; p < K_; ++p) {
    unsigned bv = 0xFFFFFFFFu;
    int bj = 0;
#pragma unroll
    for (int j = 0; j < 64; ++j) {
      if (u[j] < bv) { bv = u[j]; bj = j; }
    }
    unsigned bn = (unsigned)(bj * 64 + lane);
#pragma unroll
    for (int off = 32; off > 0; off >>= 1) {
      unsigned ov = __shfl_down(bv, off);
      unsigned on = __shfl_down(bn, off);
      if (ov < bv || (ov == bv && on < bn)) { bv = ov; bn = on; }
    }
    unsigned gn = __shfl(bn, 0);
    if (lane == p) keep = gn;
    if ((gn & 63u) == (unsigned)lane) {
      int gj = gn >> 6;
#pragma unroll
      for (int j = 0; j < 64; ++j)
        if (j == gj) u[j] = 0xFFFFFFFFu;
    }
  }
  if (lane < K_) nn_idx[(size_t)bs * K_ + lane] = (int)keep;
}

// ---------------------------------------------------------------- weight transpose
__global__ void prep_wT(const float* __restrict__ w0, const float* __restrict__ w1,
                        const float* __restrict__ w2, float* __restrict__ wT0,
                        float* __restrict__ wT1, float* __restrict__ wT2) {
  int t = blockIdx.x * 256 + threadIdx.x;
  if (t < 64 * 67) { int o = t / 67, c = t % 67; wT0[c * 64 + o] = w0[t]; }
  if (t < 64 * 64) { int o = t >> 6, c = t & 63; wT1[c * 64 + o] = w1[t]; }
  if (t < 128 * 64) { int o = t >> 6, c = t & 63; wT2[c * 128 + o] = w2[t]; }
}

// ---------------------------------------------------------------- stats helper
__device__ __forceinline__ void stats_accum(float acc[8][8], const float* __restrict__ bias_,
                                            int obase, int o0, int mq,
                                            float* __restrict__ stp) {
#pragma unroll
  for (int j = 0; j < 8; ++j) {
    float bv = bias_[obase + o0 + j];
    float s = 0.0f, q = 0.0f;
#pragma unroll
    for (int i = 0; i < 8; ++i) {
      float ya = acc[i][j] + bv;
      s += ya;
      q = fmaf(ya, ya, q);
    }
#pragma unroll
    for (int off = 1; off < 8; off <<= 1) {
      s += __shfl_xor(s, off);
      q += __shfl_xor(q, off);
    }
    if (mq == 0) {
      atomicAdd(&stp[(size_t)(obase + o0 + j) * 2 + 0], s);
      atomicAdd(&stp[(size_t)(obase + o0 + j) * 2 + 1], q);
    }
  }
}

// ================================================================ FULL path
// Phase A: 256 threads = 4 waves, each wave owns one 64-row tile.
__global__ __launch_bounds__(256) void gemm0_mat(
    const float* __restrict__ xyz, const float* __restrict__ points,
    const float* __restrict__ newxyz, const int* __restrict__ nn_idx,
    const float* __restrict__ wT0, const float* __restrict__ bias0,
    ushort_t* __restrict__ y0T, float* __restrict__ stats) {
  constexpr int MP = 68;
  __shared__ __align__(16) float xs[4][67 * MP];
  int t = threadIdx.x;
  int blk = blockIdx.x;
  int g = t >> 6, l = t & 63;
  int r = blk * 256 + t;
  int b = r >> 15;
  int sg = r >> 5;
  int idx = nn_idx[r];
  const float* xb = xyz + (size_t)b * N_ * 3;
  const float4* pb4 = reinterpret_cast<const float4*>(
      points + (size_t)b * N_ * 64 + (size_t)idx * 64);
  float nx0 = newxyz[(size_t)sg * 3 + 0];
  float nx1 = newxyz[(size_t)sg * 3 + 1];
  float nx2 = newxyz[(size_t)sg * 3 + 2];
  float* xsg = xs[g];
#pragma unroll
  for (int q = 0; q < 16; ++q) {
    float4 v = pb4[q];
    xsg[(3 + 4 * q + 0) * MP + l] = v.x;
    xsg[(3 + 4 * q + 1) * MP + l] = v.y;
    xsg[(3 + 4 * q + 2) * MP + l] = v.z;
    xsg[(3 + 4 * q + 3) * MP + l] = v.w;
  }
  xsg[0 * MP + l] = __fsub_rn(xb[idx * 3 + 0], nx0);
  xsg[1 * MP + l] = __fsub_rn(xb[idx * 3 + 1], nx1);
  xsg[2 * MP + l] = __fsub_rn(xb[idx * 3 + 2], nx2);
  __syncthreads();
  int mq = l & 7, oq = l >> 3;
  int m0 = mq * 8, o0 = oq * 8;
  int row0 = blk * 256 + g * 64;
  float acc[8][8];
#pragma unroll
  for (int i = 0; i < 8; ++i)
#pragma unroll
    for (int j = 0; j < 8; ++j) acc[i][j] = 0.0f;
#pragma unroll 2
  for (int c = 0; c < 67; ++c) {
    float4 xa = *reinterpret_cast<const float4*>(&xsg[c * MP + m0]);
    float4 xb4 = *reinterpret_cast<const float4*>(&xsg[c * MP + m0 + 4]);
    float4 wa = *reinterpret_cast<const float4*>(&wT0[c * 64 + o0]);
    float4 wb = *reinterpret_cast<const float4*>(&wT0[c * 64 + o0 + 4]);
    float xr[8] = {xa.x, xa.y, xa.z, xa.w, xb4.x, xb4.y, xb4.z, xb4.w};
    float wr[8] = {wa.x, wa.y, wa.z, wa.w, wb.x, wb.y, wb.z, wb.w};
#pragma unroll
    for (int i = 0; i < 8; ++i)
#pragma unroll
      for (int j = 0; j < 8; ++j) acc[i][j] = fmaf(xr[i], wr[j], acc[i][j]);
  }
  ushort_t* yo = y0T + row0 + m0;
#pragma unroll
  for (int j = 0; j < 8; ++j) {
    float bv = bias0[o0 + j];
    unsigned pk[4];
#pragma unroll
    for (int ii = 0; ii < 4; ++ii) {
      float a = acc[2 * ii][j] + bv;
      float c2 = acc[2 * ii + 1][j] + bv;
      pk[ii] = (unsigned)f2bf(a) | ((unsigned)f2bf(c2) << 16);
    }
    *reinterpret_cast<uint4*>(yo + (size_t)(o0 + j) * RWS) =
        make_uint4(pk[0], pk[1], pk[2], pk[3]);
  }
  stats_accum(acc, bias0, 0, o0, mq,
              stats + (size_t)((blk * 4 + g) & (NSLOT - 1)) * 64 * 2);
}

// Phase B: stream y0T with 8-deep register prefetch (HBM-latency hiding),
// bn0/relu inline, GEMM1, store y1T bf16, stats1. LDS-free.
__global__ __launch_bounds__(256) void gemm1_mat(
    const ushort_t* __restrict__ y0T, const float* __restrict__ bnp,
    const float* __restrict__ wT1, const float* __restrict__ bias1,
    ushort_t* __restrict__ y1T, float* __restrict__ stats) {
  int t = threadIdx.x;
  int blk = blockIdx.x;
  int g = t >> 6, l = t & 63;
  int row0 = blk * 256 + g * 64;
  int mq = l & 7, oq = l >> 3;
  int m0 = mq * 8, o0 = oq * 8;
  float acc[8][8];
#pragma unroll
  for (int i = 0; i < 8; ++i)
#pragma unroll
    for (int j = 0; j < 8; ++j) acc[i][j] = 0.0f;
  const ushort_t* xbase = y0T + row0 + m0;
  uint4 xv[8];
#pragma unroll 1
  for (int cb = 0; cb < 64; cb += 8) {
#pragma unroll
    for (int u2 = 0; u2 < 8; ++u2)
      xv[u2] = *reinterpret_cast<const uint4*>(xbase + (size_t)(cb + u2) * RWS);
#pragma unroll
    for (int u2 = 0; u2 < 8; ++u2) {
      int c = cb + u2;
      float sc = bnp[c], sh = bnp[64 + c];
      float xr[8];
      xr[0] = __uint_as_float(xv[u2].x << 16);
      xr[1] = __uint_as_float(xv[u2].x & 0xffff0000u);
      xr[2] = __uint_as_float(xv[u2].y << 16);
      xr[3] = __uint_as_float(xv[u2].y & 0xffff0000u);
      xr[4] = __uint_as_float(xv[u2].z << 16);
      xr[5] = __uint_as_float(xv[u2].z & 0xffff0000u);
      xr[6] = __uint_as_float(xv[u2].w << 16);
      xr[7] = __uint_as_float(xv[u2].w & 0xffff0000u);
#pragma unroll
      for (int i = 0; i < 8; ++i) xr[i] = fmaxf(fmaf(xr[i], sc, sh), 0.0f);
      float4 wa = *reinterpret_cast<const float4*>(&wT1[c * 64 + o0]);
      float4 wb = *reinterpret_cast<const float4*>(&wT1[c * 64 + o0 + 4]);
      float wr[8] = {wa.x, wa.y, wa.z, wa.w, wb.x, wb.y, wb.z, wb.w};
#pragma unroll
      for (int i = 0; i < 8; ++i)
#pragma unroll
        for (int j = 0; j < 8; ++j) acc[i][j] = fmaf(xr[i], wr[j], acc[i][j]);
    }
  }
  ushort_t* yo = y1T + row0 + m0;
#pragma unroll
  for (int j = 0; j < 8; ++j) {
    float bv = bias1[o0 + j];
    unsigned pk[4];
#pragma unroll
    for (int ii = 0; ii < 4; ++ii) {
      float a = acc[2 * ii][j] + bv;
      float c2 = acc[2 * ii + 1][j] + bv;
      pk[ii] = (unsigned)f2bf(a) | ((unsigned)f2bf(c2) << 16);
    }
    *reinterpret_cast<uint4*>(yo + (size_t)(o0 + j) * RWS) =
        make_uint4(pk[0], pk[1], pk[2], pk[3]);
  }
  stats_accum(acc, bias1, 0, o0, mq,
              stats + (size_t)((blk * 4 + g) & (NSLOT - 1)) * 64 * 2);
}

// Phase C: stream y1T with 8-deep prefetch, bn1/relu inline, GEMM2 (2 halves),
// stats2 + min/max. LDS-free.
__global__ __launch_bounds__(256) void gemm2_mat(
    const ushort_t* __restrict__ y1T, const float* __restrict__ bnp,
    const float* __restrict__ wT2, const float* __restrict__ bias2,
    float* __restrict__ stats, float* __restrict__ maxY, float* __restrict__ minY) {
  int t = threadIdx.x;
  int blk = blockIdx.x;
  int g = t >> 6, l = t & 63;
  int row0 = blk * 256 + g * 64;
  int bs0 = row0 >> 5;
  int mq = l & 7, oq = l >> 3;
  int m0 = mq * 8, o0 = oq * 8;
  const ushort_t* xbase = y1T + row0 + m0;
  float* stp = stats + (size_t)((blk * 4 + g) & (NSLOT - 1)) * 128 * 2;
  uint4 xv[8];
#pragma unroll 1
  for (int h = 0; h < 2; ++h) {
    float acc[8][8];
#pragma unroll
    for (int i = 0; i < 8; ++i)
#pragma unroll
      for (int j = 0; j < 8; ++j) acc[i][j] = 0.0f;
#pragma unroll 1
    for (int cb = 0; cb < 64; cb += 8) {
#pragma unroll
      for (int u2 = 0; u2 < 8; ++u2)
        xv[u2] = *reinterpret_cast<const uint4*>(xbase + (size_t)(cb + u2) * RWS);
#pragma unroll
      for (int u2 = 0; u2 < 8; ++u2) {
        int c = cb + u2;
        float sc = bnp[128 + c], sh = bnp[192 + c];
        float xr[8];
        xr[0] = __uint_as_float(xv[u2].x << 16);
        xr[1] = __uint_as_float(xv[u2].x & 0xffff0000u);
        xr[2] = __uint_as_float(xv[u2].y << 16);
        xr[3] = __uint_as_float(xv[u2].y & 0xffff0000u);
        xr[4] = __uint_as_float(xv[u2].z << 16);
        xr[5] = __uint_as_float(xv[u2].z & 0xffff0000u);
        xr[6] = __uint_as_float(xv[u2].w << 16);
        xr[7] = __uint_as_float(xv[u2].w & 0xffff0000u);
#pragma unroll
        for (int i = 0; i < 8; ++i) xr[i] = fmaxf(fmaf(xr[i], sc, sh), 0.0f);
        float4 wa = *reinterpret_cast<const float4*>(&wT2[c * 128 + h * 64 + o0]);
        float4 wb = *reinterpret_cast<const float4*>(&wT2[c * 128 + h * 64 + o0 + 4]);
        float wr[8] = {wa.x, wa.y, wa.z, wa.w, wb.x, wb.y, wb.z, wb.w};
#pragma unroll
        for (int i = 0; i < 8; ++i)
#pragma unroll
          for (int j = 0; j < 8; ++j) acc[i][j] = fmaf(xr[i], wr[j], acc[i][j]);
      }
    }
    stats_accum(acc, bias2, h * 64, o0, mq, stp);
#pragma unroll
    for (int j = 0; j < 8; ++j) {
      float bv = bias2[h * 64 + o0 + j];
      float mx = -3.4e38f, mn = 3.4e38f;
#pragma unroll
      for (int i = 0; i < 8; ++i) {
        float ya = acc[i][j] + bv;
        mx = fmaxf(mx, ya);
        mn = fminf(mn, ya);
      }
      mx = fmaxf(mx, __shfl_xor(mx, 1));
      mn = fminf(mn, __shfl_xor(mn, 1));
      mx = fmaxf(mx, __shfl_xor(mx, 2));
      mn = fminf(mn, __shfl_xor(mn, 2));
      if ((mq & 3) == 0) {
        size_t gidx = ((size_t)(bs0 + (mq >> 2))) * 128 + h * 64 + o0 + j;
        maxY[gidx] = mx;
        minY[gidx] = mn;
      }
    }
  }
}

// ================================================================ legacy path
template <int PHASE>
__global__ __launch_bounds__(64) void fused_layers(
    const float* __restrict__ xyz, const float* __restrict__ points,
    const float* __restrict__ newxyz, const int* __restrict__ nn_idx,
    const float* __restrict__ wT0, const float* __restrict__ bias0,
    const float* __restrict__ wT1, const float* __restrict__ bias1,
    const float* __restrict__ wT2, const float* __restrict__ bias2,
    const float* __restrict__ bnp,
    float* __restrict__ stats, float* __restrict__ maxY, float* __restrict__ minY) {
  constexpr int MP = 68;
  __shared__ __align__(16) float xs[67 * MP];
  __shared__ int nn_s[64];
  __shared__ float nx_s[6];
  int t = threadIdx.x;
  int blk = blockIdx.x;
  int row0 = blk * 64;
  int b = blk >> 9;
  int s0 = (blk & 511) * 2;
  int bs0 = b * S_ + s0;
  nn_s[t] = nn_idx[row0 + t];
  if (t < 6) nx_s[t] = newxyz[(size_t)bs0 * 3 + t];
  __syncthreads();
  const float* xb = xyz + (size_t)b * N_ * 3;
  const float* pb = points + (size_t)b * N_ * 64;
#pragma unroll 4
  for (int m = 0; m < 64; ++m) {
    int idx = nn_s[m];
    if (t < 3) {
      xs[t * MP + m] = __fsub_rn(xb[idx * 3 + t], nx_s[(m >> 5) * 3 + t]);
      xs[(64 + t) * MP + m] = pb[(size_t)idx * 64 + 61 + t];
    } else {
      xs[t * MP + m] = pb[(size_t)idx * 64 + (t - 3)];
    }
  }
  __syncthreads();
  int mq = t & 7, oq = t >> 3;
  int m0 = mq * 8, o0 = oq * 8;
  float acc[8][8];
#pragma unroll
  for (int i = 0; i < 8; ++i)
#pragma unroll
    for (int j = 0; j < 8; ++j) acc[i][j] = 0.0f;
#pragma unroll 2
  for (int c = 0; c < 67; ++c) {
    float4 xa = *reinterpret_cast<const float4*>(&xs[c * MP + m0]);
    float4 xb4 = *reinterpret_cast<const float4*>(&xs[c * MP + m0 + 4]);
    float4 wa = *reinterpret_cast<const float4*>(&wT0[c * 64 + o0]);
    float4 wb = *reinterpret_cast<const float4*>(&wT0[c * 64 + o0 + 4]);
    float xr[8] = {xa.x, xa.y, xa.z, xa.w, xb4.x, xb4.y, xb4.z, xb4.w};
    float wr[8] = {wa.x, wa.y, wa.z, wa.w, wb.x, wb.y, wb.z, wb.w};
#pragma unroll
    for (int i = 0; i < 8; ++i)
#pragma unroll
      for (int j = 0; j < 8; ++j) acc[i][j] = fmaf(xr[i], wr[j], acc[i][j]);
  }
  if constexpr (PHASE == 0) {
    stats_accum(acc, bias0, 0, o0, mq, stats + (size_t)(blk & (NSLOT - 1)) * 64 * 2);
    return;
  } else {
    __syncthreads();
#pragma unroll
    for (int j = 0; j < 8; ++j) {
      float bv = bias0[o0 + j];
      float sc = bnp[o0 + j], sh = bnp[64 + o0 + j];
#pragma unroll
      for (int i = 0; i < 8; ++i) {
        float ya = acc[i][j] + bv;
        xs[(o0 + j) * MP + (m0 + i)] = fmaxf(fmaf(ya, sc, sh), 0.0f);
      }
    }
    __syncthreads();
#pragma unroll
    for (int i = 0; i < 8; ++i)
#pragma unroll
      for (int j = 0; j < 8; ++j) acc[i][j] = 0.0f;
#pragma unroll 2
    for (int c = 0; c < 64; ++c) {
      float4 xa = *reinterpret_cast<const float4*>(&xs[c * MP + m0]);
      float4 xb4 = *reinterpret_cast<const float4*>(&xs[c * MP + m0 + 4]);
      float4 wa = *reinterpret_cast<const float4*>(&wT1[c * 64 + o0]);
      float4 wb = *reinterpret_cast<const float4*>(&wT1[c * 64 + o0 + 4]);
      float xr[8] = {xa.x, xa.y, xa.z, xa.w, xb4.x, xb4.y, xb4.z, xb4.w};
      float wr[8] = {wa.x, wa.y, wa.z, wa.w, wb.x, wb.y, wb.z, wb.w};
#pragma unroll
      for (int i = 0; i < 8; ++i)
#pragma unroll
        for (int j = 0; j < 8; ++j) acc[i][j] = fmaf(xr[i], wr[j], acc[i][j]);
    }
    if constexpr (PHASE == 1) {
      stats_accum(acc, bias1, 0, o0, mq, stats + (size_t)(blk & (NSLOT - 1)) * 64 * 2);
      return;
    } else {
      __syncthreads();
#pragma unroll
      for (int j = 0; j < 8; ++j) {
        float bv = bias1[o0 + j];
        float sc = bnp[128 + o0 + j], sh = bnp[192 + o0 + j];
#pragma unroll
        for (int i = 0; i < 8; ++i) {
          float ya = acc[i][j] + bv;
          xs[(o0 + j) * MP + (m0 + i)] = fmaxf(fmaf(ya, sc, sh), 0.0f);
        }
      }
      __syncthreads();
      float* stp = stats + (size_t)(blk & (NSLOT - 1)) * 128 * 2;
#pragma unroll 1
      for (int h = 0; h < 2; ++h) {
#pragma unroll
        for (int i = 0; i < 8; ++i)
#pragma unroll
          for (int j = 0; j < 8; ++j) acc[i][j] = 0.0f;
#pragma unroll 2
        for (int c = 0; c < 64; ++c) {
          float4 xa = *reinterpret_cast<const float4*>(&xs[c * MP + m0]);
          float4 xb4 = *reinterpret_cast<const float4*>(&xs[c * MP + m0 + 4]);
          float4 wa = *reinterpret_cast<const float4*>(&wT2[c * 128 + h * 64 + o0]);
          float4 wb = *reinterpret_cast<const float4*>(&wT2[c * 128 + h * 64 + o0 + 4]);
          float xr[8] = {xa.x, xa.y, xa.z, xa.w, xb4.x, xb4.y, xb4.z, xb4.w};
          float wr[8] = {wa.x, wa.y, wa.z, wa.w, wb.x, wb.y, wb.z, wb.w};
#pragma unroll
          for (int i = 0; i < 8; ++i)
#pragma unroll
            for (int j = 0; j < 8; ++j) acc[i][j] = fmaf(xr[i], wr[j], acc[i][j]);
        }
        stats_accum(acc, bias2, h * 64, o0, mq, stp);
#pragma unroll
        for (int j = 0; j < 8; ++j) {
          float bv = bias2[h * 64 + o0 + j];
          float mx = -3.4e38f, mn = 3.4e38f;
#pragma unroll
          for (int i = 0; i < 8; ++i) {
            float ya = acc[i][j] + bv;
            mx = fmaxf(mx, ya);
            mn = fminf(mn, ya);
          }
          mx = fmaxf(mx, __shfl_xor(mx, 1));
          mn = fminf(mn, __shfl_xor(mn, 1));
          mx = fmaxf(mx, __shfl_xor(mx, 2));
          mn = fminf(mn, __shfl_xor(mn, 2));
          if ((mq & 3) == 0) {
            size_t g = ((size_t)(bs0 + (mq >> 2))) * 128 + h * 64 + o0 + j;
            maxY[g] = mx;
            minY[g] = mn;
          }
        }
      }
    }
  }
}

// ---------------------------------------------------------------- BN finalize
__global__ void bn_finalize(const float* __restrict__ st, int cout,
                            const float* __restrict__ gamma,
                            const float* __restrict__ beta,
                            float* __restrict__ scale, float* __restrict__ shift) {
  int o = threadIdx.x;
  if (o >= cout) return;
  float s = 0.0f, q = 0.0f;
  for (int i = 0; i < NSLOT; ++i) {
    s += st[((size_t)i * cout + o) * 2 + 0];
    q += st[((size_t)i * cout + o) * 2 + 1];
  }
  float mean = s * (1.0f / CNT_F);
  float var = q * (1.0f / CNT_F) - mean * mean;
  float sc = gamma[o] / sqrtf(var + 1e-5f);
  scale[o] = sc;
  shift[o] = beta[o] - mean * sc;
}

// ---------------------------------------------------------------- pooling
__global__ __launch_bounds__(256) void pool_kernel(
    const float* __restrict__ maxY, const float* __restrict__ minY,
    const float* __restrict__ bnp, float* __restrict__ out) {
  __shared__ float tile[128 * 65];
  int b = blockIdx.x >> 4;
  int sbase = (blockIdx.x & 15) * 64;
  int t = threadIdx.x;
#pragma unroll 4
  for (int i = 0; i < 32; ++i) {
    int e = i * 256 + t;
    int sl = e >> 7, o = e & 127;
    float sc = bnp[256 + o], sh = bnp[384 + o];
    size_t g = ((size_t)(b * S_ + sbase + sl)) * 128 + o;
    float v = (sc >= 0.0f) ? maxY[g] : minY[g];
    tile[o * 65 + sl] = fmaxf(fmaf(v, sc, sh), 0.0f);
  }
  __syncthreads();
  int sl = t & 63;
  for (int o2 = t >> 6; o2 < 128; o2 += 4) {
    out[((size_t)(b * 128 + o2)) * S_ + sbase + sl] = tile[o2 * 65 + sl];
  }
}

// ---------------------------------------------------------------- launch
static inline size_t alup(size_t x) { return (x + 255) & ~(size_t)255; }

extern "C" void kernel_launch(void* const* d_in, const int* in_sizes, int n_in,
                              void* d_out, int out_size, void* d_ws, size_t ws_size,
                              hipStream_t stream) {
  (void)in_sizes; (void)n_in; (void)out_size;
  const float* xyz = (const float*)d_in[0];
  const float* points = (const float*)d_in[1];
  const float* w0 = (const float*)d_in[2];
  const float* b0 = (const float*)d_in[3];
  const float* g0 = (const float*)d_in[4];
  const float* be0 = (const float*)d_in[5];
  const float* w1 = (const float*)d_in[6];
  const float* b1 = (const float*)d_in[7];
  const float* g1 = (const float*)d_in[8];
  const float* be1 = (const float*)d_in[9];
  const float* w2 = (const float*)d_in[10];
  const float* b2 = (const float*)d_in[11];
  const float* g2 = (const float*)d_in[12];
  const float* be2 = (const float*)d_in[13];
  float* out_newxyz = (float*)d_out;
  float* out_newpts = out_newxyz + (size_t)B_ * S_ * 3;

  char* p = (char*)d_ws;
  int* fps = (int*)p;     p += alup((size_t)B_ * S_ * 4);
  int* nn = (int*)p;      p += alup((size_t)B_ * S_ * K_ * 4);
  float* ptn = (float*)p; p += alup((size_t)B_ * N_ * 4);
  float* st0 = (float*)p; p += (size_t)NSLOT * 64 * 2 * 4;
  float* st1 = (float*)p; p += (size_t)NSLOT * 64 * 2 * 4;
  float* st2 = (float*)p; p += (size_t)NSLOT * 128 * 2 * 4;
  float* bnp = (float*)p; p += alup(512 * 4);
  float* wT0 = (float*)p; p += alup(67 * 64 * 4);
  float* wT1 = (float*)p; p += alup(64 * 64 * 4);
  float* wT2 = (float*)p; p += alup(64 * 128 * 4);
  float* maxY = (float*)p; p += (size_t)B_ * S_ * 128 * 4;
  float* minY = (float*)p; p += (size_t)B_ * S_ * 128 * 4;
  char* p_common = p;
  ushort_t* y0T = (ushort_t*)p;
  ushort_t* y1T = (ushort_t*)(p + (size_t)64 * RWS * 2);
  size_t need_full = (size_t)(p_common - (char*)d_ws) + 2ull * 64 * RWS * 2;
  size_t need_legacy = (size_t)(p_common - (char*)d_ws);
  bool full = need_full <= ws_size;
  if (!full && need_legacy > ws_size) return;

  float* sc0 = bnp;       float* sh0 = bnp + 64;
  float* sc1 = bnp + 128; float* sh1 = bnp + 192;
  float* sc2 = bnp + 256; float* sh2 = bnp + 384;

  hipMemsetAsync(st0, 0, (size_t)NSLOT * (64 + 64 + 128) * 2 * 4, stream);
  prep_wT<<<32, 256, 0, stream>>>(w0, w1, w2, wT0, wT1, wT2);
  ptnorm_kernel<<<(B_ * N_) / 256, 256, 0, stream>>>(xyz, ptn);
  fps_kernel<<<B_, FPS_T, 0, stream>>>(xyz, fps, out_newxyz);
  knn_kernel<<<B_ * S_, 64, 0, stream>>>(xyz, ptn, out_newxyz, fps, nn);
  if (full) {
    gemm0_mat<<<(B_ * S_ * K_) / 256, 256, 0, stream>>>(
        xyz, points, out_newxyz, nn, wT0, b0, y0T, st0);
    bn_finalize<<<1, 128, 0, stream>>>(st0, 64, g0, be0, sc0, sh0);
    gemm1_mat<<<(B_ * S_ * K_) / 256, 256, 0, stream>>>(y0T, bnp, wT1, b1, y1T, st1);
    bn_finalize<<<1, 128, 0, stream>>>(st1, 64, g1, be1, sc1, sh1);
    gemm2_mat<<<(B_ * S_ * K_) / 256, 256, 0, stream>>>(y1T, bnp, wT2, b2, st2, maxY, minY);
    bn_finalize<<<1, 128, 0, stream>>>(st2, 128, g2, be2, sc2, sh2);
  } else {
    fused_layers<0><<<(B_ * S_) / 2, 64, 0, stream>>>(
        xyz, points, out_newxyz, nn, wT0, b0, wT1, b1, wT2, b2, bnp, st0, maxY, minY);
    bn_finalize<<<1, 128, 0, stream>>>(st0, 64, g0, be0, sc0, sh0);
    fused_layers<1><<<(B_ * S_) / 2, 64, 0, stream>>>(
        xyz, points, out_newxyz, nn, wT0, b0, wT1, b1, wT2, b2, bnp, st1, maxY, minY);
    bn_finalize<<<1, 128, 0, stream>>>(st1, 64, g1, be1, sc1, sh1);
    fused_layers<2><<<(B_ * S_) / 2, 64, 0, stream>>>(
        xyz, points, out_newxyz, nn, wT0, b0, wT1, b1, wT2, b2, bnp, st2, maxY, minY);
    bn_finalize<<<1, 128, 0, stream>>>(st2, 128, g2, be2, sc2, sh2);
  }
  pool_kernel<<<B_ * (S_ / 64), 256, 0, stream>>>(maxY, minY, bnp, out_newpts);
}

// Round 12
// 1389.102 us; speedup vs baseline: 1.2128x; 1.2128x over previous
//
#include <hip/hip_runtime.h>

#define B_ 16
#define N_ 4096
#define S_ 1024
#define K_ 32
#define NSLOT 128
#define CNT_F 524288.0f   // B*S*K
#define RWS 524288        // total rows = B*S*K

typedef unsigned short ushort_t;
typedef short short8 __attribute__((ext_vector_type(8)));
typedef float floatx4 __attribute__((ext_vector_type(4)));
union U4S8 { uint4 u; short8 v; };

__device__ __forceinline__ ushort_t f2bf(float f) {  // RNE
  unsigned u = __float_as_uint(f);
  unsigned r = (u + 0x7fffu + ((u >> 16) & 1u)) >> 16;
  return (ushort_t)r;
}
__device__ __forceinline__ unsigned pkhu(float a, float b) {  // half-up pair
  return ((__float_as_uint(a) + 0x8000u) >> 16) |
         ((__float_as_uint(b) + 0x8000u) & 0xffff0000u);
}

// unpack 8 bf16, apply bn scale/shift + relu, repack as bf16 (half-up)
__device__ __forceinline__ uint4 bn_relu_pack(uint4 xv, float4 sca, float4 scb,
                                              float4 sha, float4 shb) {
  float x0 = __uint_as_float(xv.x << 16);
  float x1 = __uint_as_float(xv.x & 0xffff0000u);
  float x2 = __uint_as_float(xv.y << 16);
  float x3 = __uint_as_float(xv.y & 0xffff0000u);
  float x4 = __uint_as_float(xv.z << 16);
  float x5 = __uint_as_float(xv.z & 0xffff0000u);
  float x6 = __uint_as_float(xv.w << 16);
  float x7 = __uint_as_float(xv.w & 0xffff0000u);
  x0 = fmaxf(fmaf(x0, sca.x, sha.x), 0.0f);
  x1 = fmaxf(fmaf(x1, sca.y, sha.y), 0.0f);
  x2 = fmaxf(fmaf(x2, sca.z, sha.z), 0.0f);
  x3 = fmaxf(fmaf(x3, sca.w, sha.w), 0.0f);
  x4 = fmaxf(fmaf(x4, scb.x, shb.x), 0.0f);
  x5 = fmaxf(fmaf(x5, scb.y, shb.y), 0.0f);
  x6 = fmaxf(fmaf(x6, scb.z, shb.z), 0.0f);
  x7 = fmaxf(fmaf(x7, scb.w, shb.w), 0.0f);
  return make_uint4(pkhu(x0, x1), pkhu(x2, x3), pkhu(x4, x5), pkhu(x6, x7));
}

// ---------------------------------------------------------------- FPS
#define FPS_T 256
#define FPS_P (N_ / FPS_T)
#define FPS_W (FPS_T / 64)

template <int CTRL>
__device__ __forceinline__ void dpp_max_u64(unsigned& hi, unsigned& lo) {
  unsigned h2 = (unsigned)__builtin_amdgcn_update_dpp(0, (int)hi, CTRL, 0xf, 0xf, true);
  unsigned l2 = (unsigned)__builtin_amdgcn_update_dpp(0, (int)lo, CTRL, 0xf, 0xf, true);
  bool take = (h2 > hi) || (h2 == hi && l2 > lo);
  hi = take ? h2 : hi;
  lo = take ? l2 : lo;
}

__global__ __launch_bounds__(FPS_T) void fps_kernel(
    const float* __restrict__ xyz, int* __restrict__ fps_idx,
    float* __restrict__ out_newxyz) {
  __shared__ float xyz_s[N_ * 3];
  __shared__ int idx_s[S_];
  __shared__ unsigned long long keys_s[2][FPS_W];
  int b = blockIdx.x, t = threadIdx.x;
  const float* xb = xyz + (size_t)b * N_ * 3;
  for (int i = t; i < N_ * 3; i += FPS_T) xyz_s[i] = xb[i];
  __syncthreads();
  float px[FPS_P], py[FPS_P], pz[FPS_P], dd[FPS_P];
#pragma unroll
  for (int j = 0; j < FPS_P; ++j) {
    int n = t + j * FPS_T;
    px[j] = xyz_s[n * 3 + 0];
    py[j] = xyz_s[n * 3 + 1];
    pz[j] = xyz_s[n * 3 + 2];
    dd[j] = 1e10f;
  }
  int fi = 0;
#pragma unroll 1
  for (int s = 0; s < S_; ++s) {
    if (t == 0) idx_s[s] = fi;
    float cx = xyz_s[fi * 3 + 0], cy = xyz_s[fi * 3 + 1], cz = xyz_s[fi * 3 + 2];
    float bv = -1.0f;
    int bi = 0;
#pragma unroll
    for (int j = 0; j < FPS_P; ++j) {
      float dx = __fsub_rn(px[j], cx);
      float dy = __fsub_rn(py[j], cy);
      float dz = __fsub_rn(pz[j], cz);
      float d = __fadd_rn(__fadd_rn(__fmul_rn(dx, dx), __fmul_rn(dy, dy)),
                          __fmul_rn(dz, dz));
      d = fminf(dd[j], d);
      dd[j] = d;
      if (d > bv) { bv = d; bi = t + j * FPS_T; }
    }
    unsigned hi = __float_as_uint(bv);
    unsigned lo = (unsigned)(N_ - 1 - bi);
    dpp_max_u64<0x111>(hi, lo);
    dpp_max_u64<0x112>(hi, lo);
    dpp_max_u64<0x114>(hi, lo);
    dpp_max_u64<0x118>(hi, lo);
    dpp_max_u64<0x142>(hi, lo);
    dpp_max_u64<0x143>(hi, lo);
    unsigned whi = (unsigned)__builtin_amdgcn_readlane((int)hi, 63);
    unsigned wlo = (unsigned)__builtin_amdgcn_readlane((int)lo, 63);
    if ((t & 63) == 0)
      keys_s[s & 1][t >> 6] = ((unsigned long long)whi << 32) | wlo;
    __syncthreads();
    unsigned long long m = keys_s[s & 1][0];
#pragma unroll
    for (int w = 1; w < FPS_W; ++w) {
      unsigned long long k = keys_s[s & 1][w];
      m = k > m ? k : m;
    }
    fi = (N_ - 1) - (int)(unsigned)(m & 0xFFFFFFFFULL);
  }
  __syncthreads();
  for (int s = t; s < S_; s += FPS_T) {
    int i = idx_s[s];
    fps_idx[b * S_ + s] = i;
    out_newxyz[((size_t)b * S_ + s) * 3 + 0] = xyz_s[i * 3 + 0];
    out_newxyz[((size_t)b * S_ + s) * 3 + 1] = xyz_s[i * 3 + 1];
    out_newxyz[((size_t)b * S_ + s) * 3 + 2] = xyz_s[i * 3 + 2];
  }
}

// ---------------------------------------------------------------- point norms
__global__ void ptnorm_kernel(const float* __restrict__ xyz, float* __restrict__ pt) {
  int i = blockIdx.x * 256 + threadIdx.x;
  float x = xyz[(size_t)i * 3 + 0];
  float y = xyz[(size_t)i * 3 + 1];
  float z = xyz[(size_t)i * 3 + 2];
  pt[i] = __fadd_rn(__fadd_rn(__fmul_rn(x, x), __fmul_rn(y, y)), __fmul_rn(z, z));
}

// ---------------------------------------------------------------- kNN (K=32)
__global__ __launch_bounds__(64) void knn_kernel(
    const float* __restrict__ xyz, const float* __restrict__ ptnorm,
    const float* __restrict__ newxyz, const int* __restrict__ fps_idx,
    int* __restrict__ nn_idx) {
  int bs = blockIdx.x;
  int b = bs >> 10;
  int lane = threadIdx.x;
  float sx = newxyz[(size_t)bs * 3 + 0];
  float sy = newxyz[(size_t)bs * 3 + 1];
  float sz = newxyz[(size_t)bs * 3 + 2];
  int fi = fps_idx[bs];
  float nxn = ptnorm[(size_t)b * N_ + fi];
  const float* xb = xyz + (size_t)b * N_ * 3;
  const float* pnb = ptnorm + (size_t)b * N_;
  unsigned u[64];
#pragma unroll
  for (int j = 0; j < 64; ++j) {
    int n = j * 64 + lane;
    float x = xb[n * 3 + 0], y = xb[n * 3 + 1], z = xb[n * 3 + 2];
    float e = __fadd_rn(__fadd_rn(__fmul_rn(sx, x), __fmul_rn(sy, y)),
                        __fmul_rn(sz, z));
    float d = __fadd_rn(__fadd_rn(nxn, pnb[n]), __fmul_rn(-2.0f, e));
    int sb = __float_as_int(d);
    u[j] = (sb < 0) ? ~((unsigned)sb) : (((unsigned)sb) | 0x80000000u);
  }
  unsigned keep = 0;
#pragma unroll 1
  for (int p = 0; p < K_; ++p) {
    unsigned bv = 0xFFFFFFFFu;
    int bj = 0;
#pragma unroll
    for (int j = 0; j < 64; ++j) {
      if (u[j] < bv) { bv = u[j]; bj = j; }
    }
    unsigned bn = (unsigned)(bj * 64 + lane);
#pragma unroll
    for (int off = 32; off > 0; off >>= 1) {
      unsigned ov = __shfl_down(bv, off);
      unsigned on = __shfl_down(bn, off);
      if (ov < bv || (ov == bv && on < bn)) { bv = ov; bn = on; }
    }
    unsigned gn = __shfl(bn, 0);
    if (lane == p) keep = gn;
    if ((gn & 63u) == (unsigned)lane) {
      int gj = gn >> 6;
#pragma unroll
      for (int j = 0; j < 64; ++j)
        if (j == gj) u[j] = 0xFFFFFFFFu;
    }
  }
  if (lane < K_) nn_idx[(size_t)bs * K_ + lane] = (int)keep;
}

// ---------------------------------------------------------------- weight prep
// wT0 fp32 transposed [c][o] for gemm0; wB1/wB2 bf16 row-major [o][c] for MFMA.
__global__ void prep_w(const float* __restrict__ w0, const float* __restrict__ w1,
                       const float* __restrict__ w2, float* __restrict__ wT0,
                       ushort_t* __restrict__ wB1, ushort_t* __restrict__ wB2) {
  int t = blockIdx.x * 256 + threadIdx.x;
  if (t < 64 * 67) { int o = t / 67, c = t % 67; wT0[c * 64 + o] = w0[t]; }
  if (t < 64 * 64) wB1[t] = f2bf(w1[t]);
  if (t < 128 * 64) wB2[t] = f2bf(w2[t]);
}

// ---------------------------------------------------------------- stats helper
__device__ __forceinline__ void stats_accum(float acc[8][8], const float* __restrict__ bias_,
                                            int obase, int o0, int mq,
                                            float* __restrict__ stp) {
#pragma unroll
  for (int j = 0; j < 8; ++j) {
    float bv = bias_[obase + o0 + j];
    float s = 0.0f, q = 0.0f;
#pragma unroll
    for (int i = 0; i < 8; ++i) {
      float ya = acc[i][j] + bv;
      s += ya;
      q = fmaf(ya, ya, q);
    }
#pragma unroll
    for (int off = 1; off < 8; off <<= 1) {
      s += __shfl_xor(s, off);
      q += __shfl_xor(q, off);
    }
    if (mq == 0) {
      atomicAdd(&stp[(size_t)(obase + o0 + j) * 2 + 0], s);
      atomicAdd(&stp[(size_t)(obase + o0 + j) * 2 + 1], q);
    }
  }
}

// ================================================================ gemm0 (fp32)
// 256 threads = 4 waves, each wave one 64-row tile; conflict-free lane=row
// gather; stores raw y0 bf16 ROW-MAJOR [row][64] (8x16B segs/lane); stats0.
__global__ __launch_bounds__(256) void gemm0_mat(
    const float* __restrict__ xyz, const float* __restrict__ points,
    const float* __restrict__ newxyz, const int* __restrict__ nn_idx,
    const float* __restrict__ wT0, const float* __restrict__ bias0,
    ushort_t* __restrict__ y0, float* __restrict__ stats) {
  constexpr int MP = 68;
  __shared__ __align__(16) float xs[4][67 * MP];
  int t = threadIdx.x;
  int blk = blockIdx.x;
  int g = t >> 6, l = t & 63;
  int r = blk * 256 + t;
  int b = r >> 15;
  int sg = r >> 5;
  int idx = nn_idx[r];
  const float* xb = xyz + (size_t)b * N_ * 3;
  const float4* pb4 = reinterpret_cast<const float4*>(
      points + (size_t)b * N_ * 64 + (size_t)idx * 64);
  float nx0 = newxyz[(size_t)sg * 3 + 0];
  float nx1 = newxyz[(size_t)sg * 3 + 1];
  float nx2 = newxyz[(size_t)sg * 3 + 2];
  float* xsg = xs[g];
#pragma unroll
  for (int q = 0; q < 16; ++q) {
    float4 v = pb4[q];
    xsg[(3 + 4 * q + 0) * MP + l] = v.x;
    xsg[(3 + 4 * q + 1) * MP + l] = v.y;
    xsg[(3 + 4 * q + 2) * MP + l] = v.z;
    xsg[(3 + 4 * q + 3) * MP + l] = v.w;
  }
  xsg[0 * MP + l] = __fsub_rn(xb[idx * 3 + 0], nx0);
  xsg[1 * MP + l] = __fsub_rn(xb[idx * 3 + 1], nx1);
  xsg[2 * MP + l] = __fsub_rn(xb[idx * 3 + 2], nx2);
  __syncthreads();
  int mq = l & 7, oq = l >> 3;
  int m0 = mq * 8, o0 = oq * 8;
  int row0 = blk * 256 + g * 64;
  float acc[8][8];
#pragma unroll
  for (int i = 0; i < 8; ++i)
#pragma unroll
    for (int j = 0; j < 8; ++j) acc[i][j] = 0.0f;
#pragma unroll 2
  for (int c = 0; c < 67; ++c) {
    float4 xa = *reinterpret_cast<const float4*>(&xsg[c * MP + m0]);
    float4 xb4 = *reinterpret_cast<const float4*>(&xsg[c * MP + m0 + 4]);
    float4 wa = *reinterpret_cast<const float4*>(&wT0[c * 64 + o0]);
    float4 wb = *reinterpret_cast<const float4*>(&wT0[c * 64 + o0 + 4]);
    float xr[8] = {xa.x, xa.y, xa.z, xa.w, xb4.x, xb4.y, xb4.z, xb4.w};
    float wr[8] = {wa.x, wa.y, wa.z, wa.w, wb.x, wb.y, wb.z, wb.w};
#pragma unroll
    for (int i = 0; i < 8; ++i)
#pragma unroll
      for (int j = 0; j < 8; ++j) acc[i][j] = fmaf(xr[i], wr[j], acc[i][j]);
  }
  float bsv[8];
#pragma unroll
  for (int j = 0; j < 8; ++j) bsv[j] = bias0[o0 + j];
  ushort_t* yo = y0 + (size_t)(row0 + m0) * 64 + o0;
#pragma unroll
  for (int i = 0; i < 8; ++i) {
    unsigned pk[4];
#pragma unroll
    for (int jj = 0; jj < 4; ++jj) {
      float a = acc[i][2 * jj] + bsv[2 * jj];
      float c2 = acc[i][2 * jj + 1] + bsv[2 * jj + 1];
      pk[jj] = (unsigned)f2bf(a) | ((unsigned)f2bf(c2) << 16);
    }
    *reinterpret_cast<uint4*>(yo + (size_t)i * 64) =
        make_uint4(pk[0], pk[1], pk[2], pk[3]);
  }
  stats_accum(acc, bias0, 0, o0, mq,
              stats + (size_t)((blk * 4 + g) & (NSLOT - 1)) * 64 * 2);
}

// ================================================================ gemm1 (MFMA)
// Wave handles 16 tiles of 16 rows (256 rows). A = bn0/relu(y0) repacked bf16;
// B = wB1 bf16 (preloaded frags). D via LDS bounce -> row-major y1. stats1.
__global__ __launch_bounds__(256) void gemm1_mfma(
    const ushort_t* __restrict__ y0, const float* __restrict__ bnp,
    const ushort_t* __restrict__ wB1, const float* __restrict__ bias1,
    ushort_t* __restrict__ y1, float* __restrict__ stats) {
  __shared__ __align__(16) float lt[4][16 * 68];
  int t = threadIdx.x;
  int w = t >> 6, l = t & 63;
  int n = l & 15, quad = l >> 4;
  U4S8 bf[4][2];
#pragma unroll
  for (int nt = 0; nt < 4; ++nt)
#pragma unroll
    for (int kc = 0; kc < 2; ++kc)
      bf[nt][kc].u = *reinterpret_cast<const uint4*>(
          wB1 + (size_t)(nt * 16 + n) * 64 + kc * 32 + quad * 8);
  float4 scA[2], scB[2], shA[2], shB[2];
#pragma unroll
  for (int kc = 0; kc < 2; ++kc) {
    int cb = kc * 32 + quad * 8;
    scA[kc] = *reinterpret_cast<const float4*>(&bnp[cb]);
    scB[kc] = *reinterpret_cast<const float4*>(&bnp[cb + 4]);
    shA[kc] = *reinterpret_cast<const float4*>(&bnp[64 + cb]);
    shB[kc] = *reinterpret_cast<const float4*>(&bnp[64 + cb + 4]);
  }
  float b1v[4], ssum[4], ssq[4];
#pragma unroll
  for (int nt = 0; nt < 4; ++nt) {
    b1v[nt] = bias1[nt * 16 + n];
    ssum[nt] = 0.0f;
    ssq[nt] = 0.0f;
  }
  int rowbase0 = blockIdx.x * 1024 + w * 256;
  float* ltw = lt[w];
  int rr = l & 15, qt = l >> 4;
#pragma unroll 1
  for (int tile = 0; tile < 16; ++tile) {
    int rb = rowbase0 + tile * 16;
    U4S8 af[2];
#pragma unroll
    for (int kc = 0; kc < 2; ++kc) {
      uint4 xv = *reinterpret_cast<const uint4*>(
          y0 + (size_t)(rb + n) * 64 + kc * 32 + quad * 8);
      af[kc].u = bn_relu_pack(xv, scA[kc], scB[kc], shA[kc], shB[kc]);
    }
    floatx4 acc[4];
#pragma unroll
    for (int nt = 0; nt < 4; ++nt) acc[nt] = floatx4{0.f, 0.f, 0.f, 0.f};
#pragma unroll
    for (int kc = 0; kc < 2; ++kc)
#pragma unroll
      for (int nt = 0; nt < 4; ++nt)
        acc[nt] = __builtin_amdgcn_mfma_f32_16x16x32_bf16(
            af[kc].v, bf[nt][kc].v, acc[nt], 0, 0, 0);
#pragma unroll
    for (int nt = 0; nt < 4; ++nt)
#pragma unroll
      for (int rI = 0; rI < 4; ++rI) {
        float ys = acc[nt][rI] + b1v[nt];
        ssum[nt] += ys;
        ssq[nt] = fmaf(ys, ys, ssq[nt]);
        ltw[(quad * 4 + rI) * 68 + nt * 16 + n] = ys;
      }
    const float* lrow = ltw + rr * 68 + qt * 16;
    float4 va = *reinterpret_cast<const float4*>(lrow);
    float4 vb = *reinterpret_cast<const float4*>(lrow + 4);
    float4 vc = *reinterpret_cast<const float4*>(lrow + 8);
    float4 vd = *reinterpret_cast<const float4*>(lrow + 12);
    ushort_t* yo = y1 + (size_t)(rb + rr) * 64 + qt * 16;
    *reinterpret_cast<uint4*>(yo) =
        make_uint4(pkhu(va.x, va.y), pkhu(va.z, va.w), pkhu(vb.x, vb.y), pkhu(vb.z, vb.w));
    *reinterpret_cast<uint4*>(yo + 8) =
        make_uint4(pkhu(vc.x, vc.y), pkhu(vc.z, vc.w), pkhu(vd.x, vd.y), pkhu(vd.z, vd.w));
  }
  float* stp = stats + (size_t)((blockIdx.x * 4 + w) & (NSLOT - 1)) * 64 * 2;
#pragma unroll
  for (int nt = 0; nt < 4; ++nt) {
    float s = ssum[nt], q = ssq[nt];
    s += __shfl_down(s, 16); q += __shfl_down(q, 16);
    s += __shfl_down(s, 32); q += __shfl_down(q, 32);
    if (l < 16) {
      atomicAdd(&stp[(size_t)(nt * 16 + l) * 2 + 0], s);
      atomicAdd(&stp[(size_t)(nt * 16 + l) * 2 + 1], q);
    }
  }
}

// ================================================================ gemm2 (MFMA)
// Wave: 16 tiles (256 rows = 8 s). A = bn1/relu(y1); B = wB2 (8 nt frags).
// No y2 store: stats2 + per-s max/min of raw y2 (pool commutes with affine).
__global__ __launch_bounds__(256) void gemm2_mfma(
    const ushort_t* __restrict__ y1, const float* __restrict__ bnp,
    const ushort_t* __restrict__ wB2, const float* __restrict__ bias2,
    float* __restrict__ stats, float* __restrict__ maxY, float* __restrict__ minY) {
  int t = threadIdx.x;
  int w = t >> 6, l = t & 63;
  int n = l & 15, quad = l >> 4;
  U4S8 bf[8][2];
#pragma unroll
  for (int nt = 0; nt < 8; ++nt)
#pragma unroll
    for (int kc = 0; kc < 2; ++kc)
      bf[nt][kc].u = *reinterpret_cast<const uint4*>(
          wB2 + (size_t)(nt * 16 + n) * 64 + kc * 32 + quad * 8);
  float4 scA[2], scB[2], shA[2], shB[2];
#pragma unroll
  for (int kc = 0; kc < 2; ++kc) {
    int cb = kc * 32 + quad * 8;
    scA[kc] = *reinterpret_cast<const float4*>(&bnp[128 + cb]);
    scB[kc] = *reinterpret_cast<const float4*>(&bnp[128 + cb + 4]);
    shA[kc] = *reinterpret_cast<const float4*>(&bnp[192 + cb]);
    shB[kc] = *reinterpret_cast<const float4*>(&bnp[192 + cb + 4]);
  }
  float b2v[8], ssum[8], ssq[8], mxv[8], mnv[8];
#pragma unroll
  for (int nt = 0; nt < 8; ++nt) {
    b2v[nt] = bias2[nt * 16 + n];
    ssum[nt] = 0.0f;
    ssq[nt] = 0.0f;
    mxv[nt] = -3.4e38f;
    mnv[nt] = 3.4e38f;
  }
  int rowbase0 = blockIdx.x * 1024 + w * 256;
#pragma unroll 1
  for (int tile = 0; tile < 16; ++tile) {
    int rb = rowbase0 + tile * 16;
    U4S8 af[2];
#pragma unroll
    for (int kc = 0; kc < 2; ++kc) {
      uint4 xv = *reinterpret_cast<const uint4*>(
          y1 + (size_t)(rb + n) * 64 + kc * 32 + quad * 8);
      af[kc].u = bn_relu_pack(xv, scA[kc], scB[kc], shA[kc], shB[kc]);
    }
    floatx4 acc[8];
#pragma unroll
    for (int nt = 0; nt < 8; ++nt) acc[nt] = floatx4{0.f, 0.f, 0.f, 0.f};
#pragma unroll
    for (int kc = 0; kc < 2; ++kc)
#pragma unroll
      for (int nt = 0; nt < 8; ++nt)
        acc[nt] = __builtin_amdgcn_mfma_f32_16x16x32_bf16(
            af[kc].v, bf[nt][kc].v, acc[nt], 0, 0, 0);
#pragma unroll
    for (int nt = 0; nt < 8; ++nt)
#pragma unroll
      for (int rI = 0; rI < 4; ++rI) {
        float ya = acc[nt][rI] + b2v[nt];
        ssum[nt] += ya;
        ssq[nt] = fmaf(ya, ya, ssq[nt]);
        mxv[nt] = fmaxf(mxv[nt], ya);
        mnv[nt] = fminf(mnv[nt], ya);
      }
    if (tile & 1) {
      int sidx = (rowbase0 >> 5) + (tile >> 1);
#pragma unroll
      for (int nt = 0; nt < 8; ++nt) {
        float mx = mxv[nt], mn = mnv[nt];
        mx = fmaxf(mx, __shfl_down(mx, 16));
        mn = fminf(mn, __shfl_down(mn, 16));
        mx = fmaxf(mx, __shfl_down(mx, 32));
        mn = fminf(mn, __shfl_down(mn, 32));
        if (l < 16) {
          maxY[(size_t)sidx * 128 + nt * 16 + l] = mx;
          minY[(size_t)sidx * 128 + nt * 16 + l] = mn;
        }
        mxv[nt] = -3.4e38f;
        mnv[nt] = 3.4e38f;
      }
    }
  }
  float* stp = stats + (size_t)((blockIdx.x * 4 + w) & (NSLOT - 1)) * 128 * 2;
#pragma unroll
  for (int nt = 0; nt < 8; ++nt) {
    float s = ssum[nt], q = ssq[nt];
    s += __shfl_down(s, 16); q += __shfl_down(q, 16);
    s += __shfl_down(s, 32); q += __shfl_down(q, 32);
    if (l < 16) {
      atomicAdd(&stp[(size_t)(nt * 16 + l) * 2 + 0], s);
      atomicAdd(&stp[(size_t)(nt * 16 + l) * 2 + 1], q);
    }
  }
}

// ---------------------------------------------------------------- BN finalize
__global__ void bn_finalize(const float* __restrict__ st, int cout,
                            const float* __restrict__ gamma,
                            const float* __restrict__ beta,
                            float* __restrict__ scale, float* __restrict__ shift) {
  int o = threadIdx.x;
  if (o >= cout) return;
  float s = 0.0f, q = 0.0f;
  for (int i = 0; i < NSLOT; ++i) {
    s += st[((size_t)i * cout + o) * 2 + 0];
    q += st[((size_t)i * cout + o) * 2 + 1];
  }
  float mean = s * (1.0f / CNT_F);
  float var = q * (1.0f / CNT_F) - mean * mean;
  float sc = gamma[o] / sqrtf(var + 1e-5f);
  scale[o] = sc;
  shift[o] = beta[o] - mean * sc;
}

// ---------------------------------------------------------------- pooling
__global__ __launch_bounds__(256) void pool_kernel(
    const float* __restrict__ maxY, const float* __restrict__ minY,
    const float* __restrict__ bnp, float* __restrict__ out) {
  __shared__ float tile[128 * 65];
  int b = blockIdx.x >> 4;
  int sbase = (blockIdx.x & 15) * 64;
  int t = threadIdx.x;
#pragma unroll 4
  for (int i = 0; i < 32; ++i) {
    int e = i * 256 + t;
    int sl = e >> 7, o = e & 127;
    float sc = bnp[256 + o], sh = bnp[384 + o];
    size_t g = ((size_t)(b * S_ + sbase + sl)) * 128 + o;
    float v = (sc >= 0.0f) ? maxY[g] : minY[g];
    tile[o * 65 + sl] = fmaxf(fmaf(v, sc, sh), 0.0f);
  }
  __syncthreads();
  int sl = t & 63;
  for (int o2 = t >> 6; o2 < 128; o2 += 4) {
    out[((size_t)(b * 128 + o2)) * S_ + sbase + sl] = tile[o2 * 65 + sl];
  }
}

// ---------------------------------------------------------------- launch
static inline size_t alup(size_t x) { return (x + 255) & ~(size_t)255; }

extern "C" void kernel_launch(void* const* d_in, const int* in_sizes, int n_in,
                              void* d_out, int out_size, void* d_ws, size_t ws_size,
                              hipStream_t stream) {
  (void)in_sizes; (void)n_in; (void)out_size;
  const float* xyz = (const float*)d_in[0];
  const float* points = (const float*)d_in[1];
  const float* w0 = (const float*)d_in[2];
  const float* b0 = (const float*)d_in[3];
  const float* g0 = (const float*)d_in[4];
  const float* be0 = (const float*)d_in[5];
  const float* w1 = (const float*)d_in[6];
  const float* b1 = (const float*)d_in[7];
  const float* g1 = (const float*)d_in[8];
  const float* be1 = (const float*)d_in[9];
  const float* w2 = (const float*)d_in[10];
  const float* b2 = (const float*)d_in[11];
  const float* g2 = (const float*)d_in[12];
  const float* be2 = (const float*)d_in[13];
  float* out_newxyz = (float*)d_out;
  float* out_newpts = out_newxyz + (size_t)B_ * S_ * 3;

  char* p = (char*)d_ws;
  int* fps = (int*)p;     p += alup((size_t)B_ * S_ * 4);
  int* nn = (int*)p;      p += alup((size_t)B_ * S_ * K_ * 4);
  float* ptn = (float*)p; p += alup((size_t)B_ * N_ * 4);
  float* st0 = (float*)p; p += (size_t)NSLOT * 64 * 2 * 4;
  float* st1 = (float*)p; p += (size_t)NSLOT * 64 * 2 * 4;
  float* st2 = (float*)p; p += (size_t)NSLOT * 128 * 2 * 4;
  float* bnp = (float*)p; p += alup(512 * 4);
  float* wT0 = (float*)p; p += alup(67 * 64 * 4);
  ushort_t* wB1 = (ushort_t*)p; p += alup(64 * 64 * 2);
  ushort_t* wB2 = (ushort_t*)p; p += alup(128 * 64 * 2);
  float* maxY = (float*)p; p += (size_t)B_ * S_ * 128 * 4;
  float* minY = (float*)p; p += (size_t)B_ * S_ * 128 * 4;
  ushort_t* y0 = (ushort_t*)p; p += (size_t)RWS * 64 * 2;
  ushort_t* y1 = (ushort_t*)p; p += (size_t)RWS * 64 * 2;
  if ((size_t)(p - (char*)d_ws) > ws_size) return;  // visible failure

  float* sc0 = bnp;       float* sh0 = bnp + 64;
  float* sc1 = bnp + 128; float* sh1 = bnp + 192;
  float* sc2 = bnp + 256; float* sh2 = bnp + 384;

  hipMemsetAsync(st0, 0, (size_t)NSLOT * (64 + 64 + 128) * 2 * 4, stream);
  prep_w<<<32, 256, 0, stream>>>(w0, w1, w2, wT0, wB1, wB2);
  ptnorm_kernel<<<(B_ * N_) / 256, 256, 0, stream>>>(xyz, ptn);
  fps_kernel<<<B_, FPS_T, 0, stream>>>(xyz, fps, out_newxyz);
  knn_kernel<<<B_ * S_, 64, 0, stream>>>(xyz, ptn, out_newxyz, fps, nn);
  gemm0_mat<<<RWS / 256, 256, 0, stream>>>(
      xyz, points, out_newxyz, nn, wT0, b0, y0, st0);
  bn_finalize<<<1, 128, 0, stream>>>(st0, 64, g0, be0, sc0, sh0);
  gemm1_mfma<<<RWS / 1024, 256, 0, stream>>>(y0, bnp, wB1, b1, y1, st1);
  bn_finalize<<<1, 128, 0, stream>>>(st1, 64, g1, be1, sc1, sh1);
  gemm2_mfma<<<RWS / 1024, 256, 0, stream>>>(y1, bnp, wB2, b2, st2, maxY, minY);
  bn_finalize<<<1, 128, 0, stream>>>(st2, 128, g2, be2, sc2, sh2);
  pool_kernel<<<B_ * (S_ / 64), 256, 0, stream>>>(maxY, minY, bnp, out_newpts);
}

// Round 13
// 1263.940 us; speedup vs baseline: 1.3329x; 1.0990x over previous
//
#include <hip/hip_runtime.h>

#define B_ 16
#define N_ 4096
#define S_ 1024
#define K_ 32
#define NSLOT 128
#define CNT_F 524288.0f   // B*S*K
#define RWS 524288        // total rows = B*S*K

typedef unsigned short ushort_t;
typedef short short8 __attribute__((ext_vector_type(8)));
typedef float floatx4 __attribute__((ext_vector_type(4)));
union U4S8 { uint4 u; short8 v; };

__device__ __forceinline__ ushort_t f2bf(float f) {  // RNE
  unsigned u = __float_as_uint(f);
  unsigned r = (u + 0x7fffu + ((u >> 16) & 1u)) >> 16;
  return (ushort_t)r;
}
__device__ __forceinline__ unsigned pkrne(float a, float b) {
  return (unsigned)f2bf(a) | ((unsigned)f2bf(b) << 16);
}
__device__ __forceinline__ unsigned pkhu(float a, float b) {  // half-up pair
  return ((__float_as_uint(a) + 0x8000u) >> 16) |
         ((__float_as_uint(b) + 0x8000u) & 0xffff0000u);
}

// unpack 8 bf16, apply bn scale/shift + relu, repack as bf16 (half-up)
__device__ __forceinline__ uint4 bn_relu_pack(uint4 xv, float4 sca, float4 scb,
                                              float4 sha, float4 shb) {
  float x0 = __uint_as_float(xv.x << 16);
  float x1 = __uint_as_float(xv.x & 0xffff0000u);
  float x2 = __uint_as_float(xv.y << 16);
  float x3 = __uint_as_float(xv.y & 0xffff0000u);
  float x4 = __uint_as_float(xv.z << 16);
  float x5 = __uint_as_float(xv.z & 0xffff0000u);
  float x6 = __uint_as_float(xv.w << 16);
  float x7 = __uint_as_float(xv.w & 0xffff0000u);
  x0 = fmaxf(fmaf(x0, sca.x, sha.x), 0.0f);
  x1 = fmaxf(fmaf(x1, sca.y, sha.y), 0.0f);
  x2 = fmaxf(fmaf(x2, sca.z, sha.z), 0.0f);
  x3 = fmaxf(fmaf(x3, sca.w, sha.w), 0.0f);
  x4 = fmaxf(fmaf(x4, scb.x, shb.x), 0.0f);
  x5 = fmaxf(fmaf(x5, scb.y, shb.y), 0.0f);
  x6 = fmaxf(fmaf(x6, scb.z, shb.z), 0.0f);
  x7 = fmaxf(fmaf(x7, scb.w, shb.w), 0.0f);
  return make_uint4(pkhu(x0, x1), pkhu(x2, x3), pkhu(x4, x5), pkhu(x6, x7));
}

// ---------------------------------------------------------------- FPS
#define FPS_T 256
#define FPS_P (N_ / FPS_T)
#define FPS_W (FPS_T / 64)

template <int CTRL>
__device__ __forceinline__ void dpp_max_u64(unsigned& hi, unsigned& lo) {
  unsigned h2 = (unsigned)__builtin_amdgcn_update_dpp(0, (int)hi, CTRL, 0xf, 0xf, true);
  unsigned l2 = (unsigned)__builtin_amdgcn_update_dpp(0, (int)lo, CTRL, 0xf, 0xf, true);
  bool take = (h2 > hi) || (h2 == hi && l2 > lo);
  hi = take ? h2 : hi;
  lo = take ? l2 : lo;
}

__global__ __launch_bounds__(FPS_T) void fps_kernel(
    const float* __restrict__ xyz, int* __restrict__ fps_idx,
    float* __restrict__ out_newxyz) {
  __shared__ float xyz_s[N_ * 3];
  __shared__ int idx_s[S_];
  __shared__ unsigned long long keys_s[2][FPS_W];
  int b = blockIdx.x, t = threadIdx.x;
  const float* xb = xyz + (size_t)b * N_ * 3;
  for (int i = t; i < N_ * 3; i += FPS_T) xyz_s[i] = xb[i];
  __syncthreads();
  float px[FPS_P], py[FPS_P], pz[FPS_P], dd[FPS_P];
#pragma unroll
  for (int j = 0; j < FPS_P; ++j) {
    int n = t + j * FPS_T;
    px[j] = xyz_s[n * 3 + 0];
    py[j] = xyz_s[n * 3 + 1];
    pz[j] = xyz_s[n * 3 + 2];
    dd[j] = 1e10f;
  }
  int fi = 0;
#pragma unroll 1
  for (int s = 0; s < S_; ++s) {
    if (t == 0) idx_s[s] = fi;
    float cx = xyz_s[fi * 3 + 0], cy = xyz_s[fi * 3 + 1], cz = xyz_s[fi * 3 + 2];
    float bv = -1.0f;
    int bi = 0;
#pragma unroll
    for (int j = 0; j < FPS_P; ++j) {
      float dx = __fsub_rn(px[j], cx);
      float dy = __fsub_rn(py[j], cy);
      float dz = __fsub_rn(pz[j], cz);
      float d = __fadd_rn(__fadd_rn(__fmul_rn(dx, dx), __fmul_rn(dy, dy)),
                          __fmul_rn(dz, dz));
      d = fminf(dd[j], d);
      dd[j] = d;
      if (d > bv) { bv = d; bi = t + j * FPS_T; }
    }
    unsigned hi = __float_as_uint(bv);
    unsigned lo = (unsigned)(N_ - 1 - bi);
    dpp_max_u64<0x111>(hi, lo);
    dpp_max_u64<0x112>(hi, lo);
    dpp_max_u64<0x114>(hi, lo);
    dpp_max_u64<0x118>(hi, lo);
    dpp_max_u64<0x142>(hi, lo);
    dpp_max_u64<0x143>(hi, lo);
    unsigned whi = (unsigned)__builtin_amdgcn_readlane((int)hi, 63);
    unsigned wlo = (unsigned)__builtin_amdgcn_readlane((int)lo, 63);
    if ((t & 63) == 0)
      keys_s[s & 1][t >> 6] = ((unsigned long long)whi << 32) | wlo;
    __syncthreads();
    unsigned long long m = keys_s[s & 1][0];
#pragma unroll
    for (int w = 1; w < FPS_W; ++w) {
      unsigned long long k = keys_s[s & 1][w];
      m = k > m ? k : m;
    }
    fi = (N_ - 1) - (int)(unsigned)(m & 0xFFFFFFFFULL);
  }
  __syncthreads();
  for (int s = t; s < S_; s += FPS_T) {
    int i = idx_s[s];
    fps_idx[b * S_ + s] = i;
    out_newxyz[((size_t)b * S_ + s) * 3 + 0] = xyz_s[i * 3 + 0];
    out_newxyz[((size_t)b * S_ + s) * 3 + 1] = xyz_s[i * 3 + 1];
    out_newxyz[((size_t)b * S_ + s) * 3 + 2] = xyz_s[i * 3 + 2];
  }
}

// ---------------------------------------------------------------- prep (ptnorm + weights)
// grid 256x256: every thread does one ptnorm elem; low ids also prep weights.
__global__ __launch_bounds__(256) void prep_all(
    const float* __restrict__ xyz, float* __restrict__ pt,
    const float* __restrict__ w0, const float* __restrict__ w1,
    const float* __restrict__ w2, ushort_t* __restrict__ wB0,
    ushort_t* __restrict__ wB1, ushort_t* __restrict__ wB2) {
  int i = blockIdx.x * 256 + threadIdx.x;  // < 65536 = B*N
  float x = xyz[(size_t)i * 3 + 0];
  float y = xyz[(size_t)i * 3 + 1];
  float z = xyz[(size_t)i * 3 + 2];
  pt[i] = __fadd_rn(__fadd_rn(__fmul_rn(x, x), __fmul_rn(y, y)), __fmul_rn(z, z));
  // wB0: [o][96] = [p-weights(64), xyz-weights(3), zeros(29)]
  if (i < 64 * 96) {
    int o = i / 96, c = i % 96;
    ushort_t v = 0;
    if (c < 64) v = f2bf(w0[o * 67 + 3 + c]);
    else if (c < 67) v = f2bf(w0[o * 67 + (c - 64)]);
    wB0[i] = v;
  }
  if (i < 64 * 64) wB1[i] = f2bf(w1[i]);
  if (i < 128 * 64) wB2[i] = f2bf(w2[i]);
}

// ---------------------------------------------------------------- kNN (K=32)
__global__ __launch_bounds__(64) void knn_kernel(
    const float* __restrict__ xyz, const float* __restrict__ ptnorm,
    const float* __restrict__ newxyz, const int* __restrict__ fps_idx,
    int* __restrict__ nn_idx) {
  int bs = blockIdx.x;
  int b = bs >> 10;
  int lane = threadIdx.x;
  float sx = newxyz[(size_t)bs * 3 + 0];
  float sy = newxyz[(size_t)bs * 3 + 1];
  float sz = newxyz[(size_t)bs * 3 + 2];
  int fi = fps_idx[bs];
  float nxn = ptnorm[(size_t)b * N_ + fi];
  const float* xb = xyz + (size_t)b * N_ * 3;
  const float* pnb = ptnorm + (size_t)b * N_;
  unsigned u[64];
#pragma unroll
  for (int j = 0; j < 64; ++j) {
    int n = j * 64 + lane;
    float x = xb[n * 3 + 0], y = xb[n * 3 + 1], z = xb[n * 3 + 2];
    float e = __fadd_rn(__fadd_rn(__fmul_rn(sx, x), __fmul_rn(sy, y)),
                        __fmul_rn(sz, z));
    float d = __fadd_rn(__fadd_rn(nxn, pnb[n]), __fmul_rn(-2.0f, e));
    int sb = __float_as_int(d);
    u[j] = (sb < 0) ? ~((unsigned)sb) : (((unsigned)sb) | 0x80000000u);
  }
  unsigned keep = 0;
#pragma unroll 1
  for (int p = 0; p < K_; ++p) {
    unsigned bv = 0xFFFFFFFFu;
    int bj = 0;
#pragma unroll
    for (int j = 0; j < 64; ++j) {
      if (u[j] < bv) { bv = u[j]; bj = j; }
    }
    unsigned bn = (unsigned)(bj * 64 + lane);
#pragma unroll
    for (int off = 32; off > 0; off >>= 1) {
      unsigned ov = __shfl_down(bv, off);
      unsigned on = __shfl_down(bn, off);
      if (ov < bv || (ov == bv && on < bn)) { bv = ov; bn = on; }
    }
    unsigned gn = __shfl(bn, 0);
    if (lane == p) keep = gn;
    if ((gn & 63u) == (unsigned)lane) {
      int gj = gn >> 6;
#pragma unroll
      for (int j = 0; j < 64; ++j)
        if (j == gj) u[j] = 0xFFFFFFFFu;
    }
  }
  if (lane < K_) nn_idx[(size_t)bs * K_ + lane] = (int)keep;
}

// ================================================================ gemm0 (MFMA)
// Wave: 16 tiles of 16 rows. A gathered directly in fragment shape from
// points (fp32->bf16) + xyz-diff in k-chunk 2 (wB0 zero-padded to K=96).
// D via LDS bounce -> row-major y0 bf16. stats0.
__global__ __launch_bounds__(256) void gemm0_mfma(
    const float* __restrict__ xyz, const float* __restrict__ points,
    const float* __restrict__ newxyz, const int* __restrict__ nn_idx,
    const ushort_t* __restrict__ wB0, const float* __restrict__ bias0,
    ushort_t* __restrict__ y0, float* __restrict__ stats) {
  __shared__ __align__(16) float lt[4][16 * 68];
  int t = threadIdx.x;
  int w = t >> 6, l = t & 63;
  int n = l & 15, quad = l >> 4;
  U4S8 bf[4][3];
#pragma unroll
  for (int nt = 0; nt < 4; ++nt)
#pragma unroll
    for (int kc = 0; kc < 3; ++kc)
      bf[nt][kc].u = *reinterpret_cast<const uint4*>(
          wB0 + (size_t)(nt * 16 + n) * 96 + kc * 32 + quad * 8);
  float b0v[4], ssum[4], ssq[4];
#pragma unroll
  for (int nt = 0; nt < 4; ++nt) {
    b0v[nt] = bias0[nt * 16 + n];
    ssum[nt] = 0.0f;
    ssq[nt] = 0.0f;
  }
  int rowbase0 = blockIdx.x * 1024 + w * 256;
  float* ltw = lt[w];
#pragma unroll 1
  for (int tile = 0; tile < 16; ++tile) {
    int rb = rowbase0 + tile * 16;
    int r = rb + n;
    int b = r >> 15;
    int sg = r >> 5;
    int idx = nn_idx[r];
    const float* pbase = points + (size_t)b * N_ * 64 + (size_t)idx * 64;
    U4S8 af[3];
#pragma unroll
    for (int kc = 0; kc < 2; ++kc) {
      float4 va = *reinterpret_cast<const float4*>(pbase + kc * 32 + quad * 8);
      float4 vb = *reinterpret_cast<const float4*>(pbase + kc * 32 + quad * 8 + 4);
      af[kc].u = make_uint4(pkrne(va.x, va.y), pkrne(va.z, va.w),
                            pkrne(vb.x, vb.y), pkrne(vb.z, vb.w));
    }
    if (quad == 0) {
      const float* xb3 = xyz + (size_t)b * N_ * 3 + (size_t)idx * 3;
      float dx = __fsub_rn(xb3[0], newxyz[(size_t)sg * 3 + 0]);
      float dy = __fsub_rn(xb3[1], newxyz[(size_t)sg * 3 + 1]);
      float dz = __fsub_rn(xb3[2], newxyz[(size_t)sg * 3 + 2]);
      af[2].u = make_uint4(pkrne(dx, dy), (unsigned)f2bf(dz), 0u, 0u);
    } else {
      af[2].u = make_uint4(0u, 0u, 0u, 0u);
    }
    floatx4 acc[4];
#pragma unroll
    for (int nt = 0; nt < 4; ++nt) acc[nt] = floatx4{0.f, 0.f, 0.f, 0.f};
#pragma unroll
    for (int kc = 0; kc < 3; ++kc)
#pragma unroll
      for (int nt = 0; nt < 4; ++nt)
        acc[nt] = __builtin_amdgcn_mfma_f32_16x16x32_bf16(
            af[kc].v, bf[nt][kc].v, acc[nt], 0, 0, 0);
#pragma unroll
    for (int nt = 0; nt < 4; ++nt)
#pragma unroll
      for (int rI = 0; rI < 4; ++rI) {
        float ys = acc[nt][rI] + b0v[nt];
        ssum[nt] += ys;
        ssq[nt] = fmaf(ys, ys, ssq[nt]);
        ltw[(quad * 4 + rI) * 68 + nt * 16 + n] = ys;
      }
    const float* lrow = ltw + n * 68 + quad * 16;
    float4 va = *reinterpret_cast<const float4*>(lrow);
    float4 vb = *reinterpret_cast<const float4*>(lrow + 4);
    float4 vc = *reinterpret_cast<const float4*>(lrow + 8);
    float4 vd = *reinterpret_cast<const float4*>(lrow + 12);
    ushort_t* yo = y0 + (size_t)(rb + n) * 64 + quad * 16;
    *reinterpret_cast<uint4*>(yo) =
        make_uint4(pkhu(va.x, va.y), pkhu(va.z, va.w), pkhu(vb.x, vb.y), pkhu(vb.z, vb.w));
    *reinterpret_cast<uint4*>(yo + 8) =
        make_uint4(pkhu(vc.x, vc.y), pkhu(vc.z, vc.w), pkhu(vd.x, vd.y), pkhu(vd.z, vd.w));
  }
  float* stp = stats + (size_t)((blockIdx.x * 4 + w) & (NSLOT - 1)) * 64 * 2;
#pragma unroll
  for (int nt = 0; nt < 4; ++nt) {
    float s = ssum[nt], q = ssq[nt];
    s += __shfl_down(s, 16); q += __shfl_down(q, 16);
    s += __shfl_down(s, 32); q += __shfl_down(q, 32);
    if (l < 16) {
      atomicAdd(&stp[(size_t)(nt * 16 + l) * 2 + 0], s);
      atomicAdd(&stp[(size_t)(nt * 16 + l) * 2 + 1], q);
    }
  }
}

// ================================================================ gemm1 (MFMA)
__global__ __launch_bounds__(256) void gemm1_mfma(
    const ushort_t* __restrict__ y0, const float* __restrict__ bnp,
    const ushort_t* __restrict__ wB1, const float* __restrict__ bias1,
    ushort_t* __restrict__ y1, float* __restrict__ stats) {
  __shared__ __align__(16) float lt[4][16 * 68];
  int t = threadIdx.x;
  int w = t >> 6, l = t & 63;
  int n = l & 15, quad = l >> 4;
  U4S8 bf[4][2];
#pragma unroll
  for (int nt = 0; nt < 4; ++nt)
#pragma unroll
    for (int kc = 0; kc < 2; ++kc)
      bf[nt][kc].u = *reinterpret_cast<const uint4*>(
          wB1 + (size_t)(nt * 16 + n) * 64 + kc * 32 + quad * 8);
  float4 scA[2], scB[2], shA[2], shB[2];
#pragma unroll
  for (int kc = 0; kc < 2; ++kc) {
    int cb = kc * 32 + quad * 8;
    scA[kc] = *reinterpret_cast<const float4*>(&bnp[cb]);
    scB[kc] = *reinterpret_cast<const float4*>(&bnp[cb + 4]);
    shA[kc] = *reinterpret_cast<const float4*>(&bnp[64 + cb]);
    shB[kc] = *reinterpret_cast<const float4*>(&bnp[64 + cb + 4]);
  }
  float b1v[4], ssum[4], ssq[4];
#pragma unroll
  for (int nt = 0; nt < 4; ++nt) {
    b1v[nt] = bias1[nt * 16 + n];
    ssum[nt] = 0.0f;
    ssq[nt] = 0.0f;
  }
  int rowbase0 = blockIdx.x * 1024 + w * 256;
  float* ltw = lt[w];
#pragma unroll 1
  for (int tile = 0; tile < 16; ++tile) {
    int rb = rowbase0 + tile * 16;
    U4S8 af[2];
#pragma unroll
    for (int kc = 0; kc < 2; ++kc) {
      uint4 xv = *reinterpret_cast<const uint4*>(
          y0 + (size_t)(rb + n) * 64 + kc * 32 + quad * 8);
      af[kc].u = bn_relu_pack(xv, scA[kc], scB[kc], shA[kc], shB[kc]);
    }
    floatx4 acc[4];
#pragma unroll
    for (int nt = 0; nt < 4; ++nt) acc[nt] = floatx4{0.f, 0.f, 0.f, 0.f};
#pragma unroll
    for (int kc = 0; kc < 2; ++kc)
#pragma unroll
      for (int nt = 0; nt < 4; ++nt)
        acc[nt] = __builtin_amdgcn_mfma_f32_16x16x32_bf16(
            af[kc].v, bf[nt][kc].v, acc[nt], 0, 0, 0);
#pragma unroll
    for (int nt = 0; nt < 4; ++nt)
#pragma unroll
      for (int rI = 0; rI < 4; ++rI) {
        float ys = acc[nt][rI] + b1v[nt];
        ssum[nt] += ys;
        ssq[nt] = fmaf(ys, ys, ssq[nt]);
        ltw[(quad * 4 + rI) * 68 + nt * 16 + n] = ys;
      }
    const float* lrow = ltw + n * 68 + quad * 16;
    float4 va = *reinterpret_cast<const float4*>(lrow);
    float4 vb = *reinterpret_cast<const float4*>(lrow + 4);
    float4 vc = *reinterpret_cast<const float4*>(lrow + 8);
    float4 vd = *reinterpret_cast<const float4*>(lrow + 12);
    ushort_t* yo = y1 + (size_t)(rb + n) * 64 + quad * 16;
    *reinterpret_cast<uint4*>(yo) =
        make_uint4(pkhu(va.x, va.y), pkhu(va.z, va.w), pkhu(vb.x, vb.y), pkhu(vb.z, vb.w));
    *reinterpret_cast<uint4*>(yo + 8) =
        make_uint4(pkhu(vc.x, vc.y), pkhu(vc.z, vc.w), pkhu(vd.x, vd.y), pkhu(vd.z, vd.w));
  }
  float* stp = stats + (size_t)((blockIdx.x * 4 + w) & (NSLOT - 1)) * 64 * 2;
#pragma unroll
  for (int nt = 0; nt < 4; ++nt) {
    float s = ssum[nt], q = ssq[nt];
    s += __shfl_down(s, 16); q += __shfl_down(q, 16);
    s += __shfl_down(s, 32); q += __shfl_down(q, 32);
    if (l < 16) {
      atomicAdd(&stp[(size_t)(nt * 16 + l) * 2 + 0], s);
      atomicAdd(&stp[(size_t)(nt * 16 + l) * 2 + 1], q);
    }
  }
}

// ================================================================ gemm2 (MFMA)
__global__ __launch_bounds__(256) void gemm2_mfma(
    const ushort_t* __restrict__ y1, const float* __restrict__ bnp,
    const ushort_t* __restrict__ wB2, const float* __restrict__ bias2,
    float* __restrict__ stats, float* __restrict__ maxY, float* __restrict__ minY) {
  int t = threadIdx.x;
  int w = t >> 6, l = t & 63;
  int n = l & 15, quad = l >> 4;
  U4S8 bf[8][2];
#pragma unroll
  for (int nt = 0; nt < 8; ++nt)
#pragma unroll
    for (int kc = 0; kc < 2; ++kc)
      bf[nt][kc].u = *reinterpret_cast<const uint4*>(
          wB2 + (size_t)(nt * 16 + n) * 64 + kc * 32 + quad * 8);
  float4 scA[2], scB[2], shA[2], shB[2];
#pragma unroll
  for (int kc = 0; kc < 2; ++kc) {
    int cb = kc * 32 + quad * 8;
    scA[kc] = *reinterpret_cast<const float4*>(&bnp[128 + cb]);
    scB[kc] = *reinterpret_cast<const float4*>(&bnp[128 + cb + 4]);
    shA[kc] = *reinterpret_cast<const float4*>(&bnp[192 + cb]);
    shB[kc] = *reinterpret_cast<const float4*>(&bnp[192 + cb + 4]);
  }
  float b2v[8], ssum[8], ssq[8], mxv[8], mnv[8];
#pragma unroll
  for (int nt = 0; nt < 8; ++nt) {
    b2v[nt] = bias2[nt * 16 + n];
    ssum[nt] = 0.0f;
    ssq[nt] = 0.0f;
    mxv[nt] = -3.4e38f;
    mnv[nt] = 3.4e38f;
  }
  int rowbase0 = blockIdx.x * 1024 + w * 256;
#pragma unroll 1
  for (int tile = 0; tile < 16; ++tile) {
    int rb = rowbase0 + tile * 16;
    U4S8 af[2];
#pragma unroll
    for (int kc = 0; kc < 2; ++kc) {
      uint4 xv = *reinterpret_cast<const uint4*>(
          y1 + (size_t)(rb + n) * 64 + kc * 32 + quad * 8);
      af[kc].u = bn_relu_pack(xv, scA[kc], scB[kc], shA[kc], shB[kc]);
    }
    floatx4 acc[8];
#pragma unroll
    for (int nt = 0; nt < 8; ++nt) acc[nt] = floatx4{0.f, 0.f, 0.f, 0.f};
#pragma unroll
    for (int kc = 0; kc < 2; ++kc)
#pragma unroll
      for (int nt = 0; nt < 8; ++nt)
        acc[nt] = __builtin_amdgcn_mfma_f32_16x16x32_bf16(
            af[kc].v, bf[nt][kc].v, acc[nt], 0, 0, 0);
#pragma unroll
    for (int nt = 0; nt < 8; ++nt)
#pragma unroll
      for (int rI = 0; rI < 4; ++rI) {
        float ya = acc[nt][rI] + b2v[nt];
        ssum[nt] += ya;
        ssq[nt] = fmaf(ya, ya, ssq[nt]);
        mxv[nt] = fmaxf(mxv[nt], ya);
        mnv[nt] = fminf(mnv[nt], ya);
      }
    if (tile & 1) {
      int sidx = (rowbase0 >> 5) + (tile >> 1);
#pragma unroll
      for (int nt = 0; nt < 8; ++nt) {
        float mx = mxv[nt], mn = mnv[nt];
        mx = fmaxf(mx, __shfl_down(mx, 16));
        mn = fminf(mn, __shfl_down(mn, 16));
        mx = fmaxf(mx, __shfl_down(mx, 32));
        mn = fminf(mn, __shfl_down(mn, 32));
        if (l < 16) {
          maxY[(size_t)sidx * 128 + nt * 16 + l] = mx;
          minY[(size_t)sidx * 128 + nt * 16 + l] = mn;
        }
        mxv[nt] = -3.4e38f;
        mnv[nt] = 3.4e38f;
      }
    }
  }
  float* stp = stats + (size_t)((blockIdx.x * 4 + w) & (NSLOT - 1)) * 128 * 2;
#pragma unroll
  for (int nt = 0; nt < 8; ++nt) {
    float s = ssum[nt], q = ssq[nt];
    s += __shfl_down(s, 16); q += __shfl_down(q, 16);
    s += __shfl_down(s, 32); q += __shfl_down(q, 32);
    if (l < 16) {
      atomicAdd(&stp[(size_t)(nt * 16 + l) * 2 + 0], s);
      atomicAdd(&stp[(size_t)(nt * 16 + l) * 2 + 1], q);
    }
  }
}

// ---------------------------------------------------------------- BN finalize
__global__ void bn_finalize(const float* __restrict__ st, int cout,
                            const float* __restrict__ gamma,
                            const float* __restrict__ beta,
                            float* __restrict__ scale, float* __restrict__ shift) {
  int o = threadIdx.x;
  if (o >= cout) return;
  float s = 0.0f, q = 0.0f;
  for (int i = 0; i < NSLOT; ++i) {
    s += st[((size_t)i * cout + o) * 2 + 0];
    q += st[((size_t)i * cout + o) * 2 + 1];
  }
  float mean = s * (1.0f / CNT_F);
  float var = q * (1.0f / CNT_F) - mean * mean;
  float sc = gamma[o] / sqrtf(var + 1e-5f);
  scale[o] = sc;
  shift[o] = beta[o] - mean * sc;
}

// ---------------------------------------------------------------- pooling
__global__ __launch_bounds__(256) void pool_kernel(
    const float* __restrict__ maxY, const float* __restrict__ minY,
    const float* __restrict__ bnp, float* __restrict__ out) {
  __shared__ float tile[128 * 65];
  int b = blockIdx.x >> 4;
  int sbase = (blockIdx.x & 15) * 64;
  int t = threadIdx.x;
#pragma unroll 4
  for (int i = 0; i < 32; ++i) {
    int e = i * 256 + t;
    int sl = e >> 7, o = e & 127;
    float sc = bnp[256 + o], sh = bnp[384 + o];
    size_t g = ((size_t)(b * S_ + sbase + sl)) * 128 + o;
    float v = (sc >= 0.0f) ? maxY[g] : minY[g];
    tile[o * 65 + sl] = fmaxf(fmaf(v, sc, sh), 0.0f);
  }
  __syncthreads();
  int sl = t & 63;
  for (int o2 = t >> 6; o2 < 128; o2 += 4) {
    out[((size_t)(b * 128 + o2)) * S_ + sbase + sl] = tile[o2 * 65 + sl];
  }
}

// ---------------------------------------------------------------- launch
static inline size_t alup(size_t x) { return (x + 255) & ~(size_t)255; }

extern "C" void kernel_launch(void* const* d_in, const int* in_sizes, int n_in,
                              void* d_out, int out_size, void* d_ws, size_t ws_size,
                              hipStream_t stream) {
  (void)in_sizes; (void)n_in; (void)out_size;
  const float* xyz = (const float*)d_in[0];
  const float* points = (const float*)d_in[1];
  const float* w0 = (const float*)d_in[2];
  const float* b0 = (const float*)d_in[3];
  const float* g0 = (const float*)d_in[4];
  const float* be0 = (const float*)d_in[5];
  const float* w1 = (const float*)d_in[6];
  const float* b1 = (const float*)d_in[7];
  const float* g1 = (const float*)d_in[8];
  const float* be1 = (const float*)d_in[9];
  const float* w2 = (const float*)d_in[10];
  const float* b2 = (const float*)d_in[11];
  const float* g2 = (const float*)d_in[12];
  const float* be2 = (const float*)d_in[13];
  float* out_newxyz = (float*)d_out;
  float* out_newpts = out_newxyz + (size_t)B_ * S_ * 3;

  char* p = (char*)d_ws;
  int* fps = (int*)p;     p += alup((size_t)B_ * S_ * 4);
  int* nn = (int*)p;      p += alup((size_t)B_ * S_ * K_ * 4);
  float* ptn = (float*)p; p += alup((size_t)B_ * N_ * 4);
  float* st0 = (float*)p; p += (size_t)NSLOT * 64 * 2 * 4;
  float* st1 = (float*)p; p += (size_t)NSLOT * 64 * 2 * 4;
  float* st2 = (float*)p; p += (size_t)NSLOT * 128 * 2 * 4;
  float* bnp = (float*)p; p += alup(512 * 4);
  ushort_t* wB0 = (ushort_t*)p; p += alup(64 * 96 * 2);
  ushort_t* wB1 = (ushort_t*)p; p += alup(64 * 64 * 2);
  ushort_t* wB2 = (ushort_t*)p; p += alup(128 * 64 * 2);
  float* maxY = (float*)p; p += (size_t)B_ * S_ * 128 * 4;
  float* minY = (float*)p; p += (size_t)B_ * S_ * 128 * 4;
  ushort_t* y0 = (ushort_t*)p; p += (size_t)RWS * 64 * 2;
  ushort_t* y1 = (ushort_t*)p; p += (size_t)RWS * 64 * 2;
  if ((size_t)(p - (char*)d_ws) > ws_size) return;  // visible failure

  float* sc0 = bnp;       float* sh0 = bnp + 64;
  float* sc1 = bnp + 128; float* sh1 = bnp + 192;
  float* sc2 = bnp + 256; float* sh2 = bnp + 384;

  hipMemsetAsync(st0, 0, (size_t)NSLOT * (64 + 64 + 128) * 2 * 4, stream);
  prep_all<<<256, 256, 0, stream>>>(xyz, ptn, w0, w1, w2, wB0, wB1, wB2);
  fps_kernel<<<B_, FPS_T, 0, stream>>>(xyz, fps, out_newxyz);
  knn_kernel<<<B_ * S_, 64, 0, stream>>>(xyz, ptn, out_newxyz, fps, nn);
  gemm0_mfma<<<RWS / 1024, 256, 0, stream>>>(
      xyz, points, out_newxyz, nn, wB0, b0, y0, st0);
  bn_finalize<<<1, 128, 0, stream>>>(st0, 64, g0, be0, sc0, sh0);
  gemm1_mfma<<<RWS / 1024, 256, 0, stream>>>(y0, bnp, wB1, b1, y1, st1);
  bn_finalize<<<1, 128, 0, stream>>>(st1, 64, g1, be1, sc1, sh1);
  gemm2_mfma<<<RWS / 1024, 256, 0, stream>>>(y1, bnp, wB2, b2, st2, maxY, minY);
  bn_finalize<<<1, 128, 0, stream>>>(st2, 128, g2, be2, sc2, sh2);
  pool_kernel<<<B_ * (S_ / 64), 256, 0, stream>>>(maxY, minY, bnp, out_newpts);
}